// Round 12
// baseline (1050.818 us; speedup 1.0000x reference)
//
#include <hip/hip_runtime.h>
#include <hip/hip_fp16.h>
#include <stdint.h>

static constexpr int N_USERS = 1000000;
static constexpr int N_ITEMS = 200000;
static constexpr int N_EDGES = 25000000;

// Tile/partition geometry
static constexpr int TILE   = 16384;                 // edges per LDS-sorted tile
static constexpr int NTILES = 3;
static constexpr int CHUNK  = TILE * NTILES;         // 49152 edges per block
static constexpr int NBLK   = (N_EDGES + CHUNK - 1) / CHUNK;   // 509
static constexpr int RUNS   = NBLK * NTILES;         // 1527 (run rb covers edges [rb*TILE, ...))

static constexpr int SHIFT_U = 11;                   // users: 2048 bins/bucket
static constexpr int SHIFT_I = 9;                    // items:  512 bins/bucket
static constexpr int NB_U = (N_USERS + (1 << SHIFT_U) - 1) >> SHIFT_U;  // 489
static constexpr int NB_I = (N_ITEMS + (1 << SHIFT_I) - 1) >> SHIFT_I;  // 391

static constexpr int SCB_U = (NB_U * RUNS + 1023) / 1024;   // 730 scan blocks
static constexpr int SCB_I = (NB_I * RUNS + 1023) / 1024;   // 584

typedef float    f4 __attribute__((ext_vector_type(4)));
typedef int      i4 __attribute__((ext_vector_type(4)));
typedef uint32_t u4 __attribute__((ext_vector_type(4)));

// ---------------------------------------------------------------------------
// P1: per-block tile-sorted partition (unchanged from round 11).
// ---------------------------------------------------------------------------
template<int SHIFT, int NB>
__global__ __launch_bounds__(1024) void k_part(const float* __restrict__ w,
                                               const int* __restrict__ r,
                                               uint32_t* __restrict__ payload,
                                               uint32_t* __restrict__ starts) {
    __shared__ uint32_t stage[TILE];     // 64 KB
    __shared__ uint32_t hist[1024];      // histogram, then write cursors
    __shared__ uint32_t wsum[16];
    const int blk = blockIdx.x;
    const int t = threadIdx.x;
    const int lane = t & 63, wave = t >> 6;
    const int begin = blk * CHUNK;
    const int bend = (begin + CHUNK < N_EDGES) ? begin + CHUNK : N_EDGES;
    const uint32_t lmask = (1u << SHIFT) - 1u;

    for (int tile = 0; tile < NTILES; ++tile) {
        const int tb = begin + tile * TILE;
        int n = bend - tb;
        n = n < 0 ? 0 : (n > TILE ? TILE : n);
        const int n4 = n >> 2;                       // all boundaries %4 == 0
        const size_t mbase = (size_t)(blk * NTILES + tile) * (NB + 1);

        hist[t] = 0;
        __syncthreads();

        // 1) load r+w, build payload in regs, histogram
        uint32_t idx[16];
        uint32_t pay[16];
        #pragma unroll
        for (int k = 0; k < 4; ++k) {
            int v = t + k * 1024;
            if (v < n4) {
                i4 u = __builtin_nontemporal_load((const i4*)r + (tb >> 2) + v);
                f4 a = __builtin_nontemporal_load((const f4*)w + (tb >> 2) + v);
                idx[4 * k + 0] = (uint32_t)u.x;
                idx[4 * k + 1] = (uint32_t)u.y;
                idx[4 * k + 2] = (uint32_t)u.z;
                idx[4 * k + 3] = (uint32_t)u.w;
                pay[4 * k + 0] = (__float_as_uint(__expf(a.x)) & ~lmask) | ((uint32_t)u.x & lmask);
                pay[4 * k + 1] = (__float_as_uint(__expf(a.y)) & ~lmask) | ((uint32_t)u.y & lmask);
                pay[4 * k + 2] = (__float_as_uint(__expf(a.z)) & ~lmask) | ((uint32_t)u.z & lmask);
                pay[4 * k + 3] = (__float_as_uint(__expf(a.w)) & ~lmask) | ((uint32_t)u.w & lmask);
                atomicAdd(&hist[(uint32_t)u.x >> SHIFT], 1u);
                atomicAdd(&hist[(uint32_t)u.y >> SHIFT], 1u);
                atomicAdd(&hist[(uint32_t)u.z >> SHIFT], 1u);
                atomicAdd(&hist[(uint32_t)u.w >> SHIFT], 1u);
            }
        }
        __syncthreads();

        // 2) exclusive scan of hist[0..1023]
        uint32_t c = hist[t];
        uint32_t x = c;
        #pragma unroll
        for (int d = 1; d < 64; d <<= 1) {
            uint32_t y = __shfl_up(x, d);
            if (lane >= d) x += y;
        }
        if (lane == 63) wsum[wave] = x;
        __syncthreads();
        if (t < 16) {
            uint32_t y = wsum[t];
            uint32_t s = y;
            #pragma unroll
            for (int d = 1; d < 16; d <<= 1) {
                uint32_t z = __shfl_up(s, d, 16);
                if (t >= d) s += z;
            }
            wsum[t] = s - y;
        }
        __syncthreads();
        uint32_t excl = x - c + wsum[wave];

        if (t < NB) starts[mbase + t] = (uint32_t)tb + excl;
        if (t == 0) starts[mbase + NB] = (uint32_t)(tb + n);  // sentinel
        hist[t] = excl;                              // tile-local cursors
        __syncthreads();

        // 3) scatter into LDS stage (registers only)
        #pragma unroll
        for (int k = 0; k < 4; ++k) {
            int v = t + k * 1024;
            if (v < n4) {
                uint32_t p0 = atomicAdd(&hist[idx[4 * k + 0] >> SHIFT], 1u);
                stage[p0] = pay[4 * k + 0];
                uint32_t p1 = atomicAdd(&hist[idx[4 * k + 1] >> SHIFT], 1u);
                stage[p1] = pay[4 * k + 1];
                uint32_t p2 = atomicAdd(&hist[idx[4 * k + 2] >> SHIFT], 1u);
                stage[p2] = pay[4 * k + 2];
                uint32_t p3 = atomicAdd(&hist[idx[4 * k + 3] >> SHIFT], 1u);
                stage[p3] = pay[4 * k + 3];
            }
        }
        __syncthreads();

        // 4) coalesced dump of the sorted tile
        #pragma unroll
        for (int k = 0; k < 4; ++k) {
            int v = t + k * 1024;
            if (v < n4) {
                u4 s4 = ((const u4*)stage)[v];
                __builtin_nontemporal_store(s4, (u4*)payload + (tb >> 2) + v);
            }
        }
        __syncthreads();
    }
}

// ---------------------------------------------------------------------------
// Tiled transpose: in[R][C] -> outT[C][R].
// ---------------------------------------------------------------------------
__global__ __launch_bounds__(1024) void k_transpose(const uint32_t* __restrict__ in,
                                                    uint32_t* __restrict__ outT,
                                                    int R, int C) {
    __shared__ uint32_t tile[32][33];
    const int tx = threadIdx.x & 31, ty = threadIdx.x >> 5;
    const int r0 = blockIdx.y * 32, c0 = blockIdx.x * 32;
    int r = r0 + ty, c = c0 + tx;
    if (r < R && c < C) tile[ty][tx] = in[(size_t)r * C + c];
    __syncthreads();
    int rr = r0 + tx, cc = c0 + ty;
    if (cc < C && rr < R) outT[(size_t)cc * R + rr] = tile[tx][ty];
}

// ---------------------------------------------------------------------------
// Global scan over per-(bucket,run) counts, b-major flat order.
// cnt(b,run) = startsT[(b+1)*RUNS+run] - startsT[b*RUNS+run]   (sentinel row NB)
// scanA: per-block exclusive scan -> pre[], block sums -> bsum[]
// scanB: single-block exclusive scan of bsum
// scanC: gpos = pre + bsum -> gstart_rb[run*NB + b]
// gstart_rb row 0 (run==0) doubles as the per-bucket global base.
// ---------------------------------------------------------------------------
template<int NB>
__global__ __launch_bounds__(1024) void k_scanA(const uint32_t* __restrict__ startsT,
                                                uint32_t* __restrict__ pre,
                                                uint32_t* __restrict__ bsum) {
    __shared__ uint32_t wsum[16];
    const int t = threadIdx.x;
    const int lane = t & 63, wave = t >> 6;
    const int N = NB * RUNS;
    const int f = blockIdx.x * 1024 + t;
    uint32_t c = 0;
    if (f < N) c = startsT[f + RUNS] - startsT[f];
    uint32_t x = c;
    #pragma unroll
    for (int d = 1; d < 64; d <<= 1) {
        uint32_t y = __shfl_up(x, d);
        if (lane >= d) x += y;
    }
    if (lane == 63) wsum[wave] = x;
    __syncthreads();
    if (t < 16) {
        uint32_t y = wsum[t];
        uint32_t s = y;
        #pragma unroll
        for (int d = 1; d < 16; d <<= 1) {
            uint32_t z = __shfl_up(s, d, 16);
            if (t >= d) s += z;
        }
        wsum[t] = s - y;
    }
    __syncthreads();
    uint32_t excl = x - c + wsum[wave];
    if (f < N) pre[f] = excl;
    if (t == 1023) bsum[blockIdx.x] = excl + c;
}

__global__ __launch_bounds__(1024) void k_scanB(uint32_t* __restrict__ bsum, int nb) {
    __shared__ uint32_t wsum[16];
    const int t = threadIdx.x;
    const int lane = t & 63, wave = t >> 6;
    uint32_t c = (t < nb) ? bsum[t] : 0u;
    uint32_t x = c;
    #pragma unroll
    for (int d = 1; d < 64; d <<= 1) {
        uint32_t y = __shfl_up(x, d);
        if (lane >= d) x += y;
    }
    if (lane == 63) wsum[wave] = x;
    __syncthreads();
    if (t < 16) {
        uint32_t y = wsum[t];
        uint32_t s = y;
        #pragma unroll
        for (int d = 1; d < 16; d <<= 1) {
            uint32_t z = __shfl_up(s, d, 16);
            if (t >= d) s += z;
        }
        wsum[t] = s - y;
    }
    __syncthreads();
    if (t < nb) bsum[t] = x - c + wsum[wave];
}

template<int NB>
__global__ __launch_bounds__(1024) void k_scanC(const uint32_t* __restrict__ pre,
                                                const uint32_t* __restrict__ bsum,
                                                uint32_t* __restrict__ gstart_rb) {
    const int N = NB * RUNS;
    const int f = blockIdx.x * 1024 + threadIdx.x;
    if (f < N) {
        uint32_t gpos = pre[f] + bsum[blockIdx.x];
        int b = f / RUNS;                            // constexpr divisor -> magic mul
        int run = f - b * RUNS;
        gstart_rb[(size_t)run * NB + b] = gpos;
    }
}

// ---------------------------------------------------------------------------
// Scatter pass: block = one tile run. Coalesced-load the tile-sorted payload
// into LDS, then copy each bucket segment to its GLOBAL sorted position.
// Result: payloadB is fully sorted by bucket (contiguous slab per bucket).
// ---------------------------------------------------------------------------
template<int NB>
__global__ __launch_bounds__(1024) void k_scatter(const uint32_t* __restrict__ payloadA,
                                                  const uint32_t* __restrict__ starts,
                                                  const uint32_t* __restrict__ gstart_rb,
                                                  uint32_t* __restrict__ payloadB) {
    __shared__ uint32_t stageL[TILE];                // 64 KB
    __shared__ uint32_t srowL[NB + 1];
    __shared__ uint32_t growL[NB];
    const int rb = blockIdx.x;
    const int t = threadIdx.x;
    const int tb = rb * TILE;
    int n = N_EDGES - tb;
    n = n < 0 ? 0 : (n > TILE ? TILE : n);
    const int n4 = n >> 2;

    for (int i = t; i < NB + 1; i += 1024) srowL[i] = starts[(size_t)rb * (NB + 1) + i];
    for (int i = t; i < NB; i += 1024) growL[i] = gstart_rb[(size_t)rb * NB + i];
    #pragma unroll
    for (int k = 0; k < 4; ++k) {
        int v = t + k * 1024;
        if (v < n4)
            ((u4*)stageL)[v] = __builtin_nontemporal_load((const u4*)payloadA + (tb >> 2) + v);
    }
    __syncthreads();

    const int sub = t >> 4, sl = t & 15;             // 64 subgroups of 16 lanes
    for (int b = sub; b < NB; b += 64) {
        uint32_t s = srowL[b] - (uint32_t)tb;
        uint32_t e = srowL[b + 1] - (uint32_t)tb;
        uint32_t g = growL[b];
        for (uint32_t i = sl; i < e - s && e > s; i += 16)
            __builtin_nontemporal_store(stageL[s + i], &payloadB[g + i]);
    }
}

// ---------------------------------------------------------------------------
// P2: block = one bucket, reading its CONTIGUOUS slab of the sorted payload
// (coalesced u4 wave-loads touch 16 contiguous lines, not 64 scattered —
// this is the theory-F test). Identical LDS-atomic stream to prior rounds.
// Emits f16 reciprocals; users variant fuses exp(w0) self term + lfw0.
// ---------------------------------------------------------------------------
template<int SHIFT, int NB>
__global__ __launch_bounds__(1024) void k_bucket_seq(const uint32_t* __restrict__ payloadB,
                                                     const uint32_t* __restrict__ gstart_rb,
                                                     int nelems,
                                                     const float* __restrict__ w0,   // null for items
                                                     __half* __restrict__ recip,
                                                     float* __restrict__ lfw0) {     // null for items
    constexpr int BINS = 1 << SHIFT;
    __shared__ float bins[BINS];
    const int b = blockIdx.x;
    const int t = threadIdx.x;
    for (int i = t; i < BINS; i += 1024) bins[i] = 0.f;
    __syncthreads();

    const uint32_t lo = gstart_rb[b];                        // row run=0 = bucket base
    const uint32_t hi = (b + 1 < NB) ? gstart_rb[b + 1] : (uint32_t)N_EDGES;
    const u4* p4 = (const u4*)payloadB;
    const uint32_t j0 = lo >> 2, j1 = (hi + 3) >> 2;
    for (uint32_t j = j0 + t; j < j1; j += 1024) {
        u4 v = __builtin_nontemporal_load(&p4[j]);
        uint32_t g = j << 2;
        #pragma unroll
        for (int c = 0; c < 4; ++c) {
            uint32_t gg = g + c;
            if (gg >= lo && gg < hi) {
                uint32_t p = v[c];
                atomicAdd(&bins[p & (BINS - 1)],
                          __uint_as_float(p & ~(uint32_t)(BINS - 1)));
            }
        }
    }
    __syncthreads();

    for (int i = t; i < BINS; i += 1024) {
        int g = b * BINS + i;
        if (g < nelems) {
            float s = bins[i];
            if (w0) {
                float e = __expf(w0[g]);
                s += e;
                lfw0[g] = e / s;
            }
            recip[g] = __float2half(1.0f / s);
        }
    }
}

// ---------------------------------------------------------------------------
// Per-edge finalize for ONE relation, unrolled x4 (16 gathers in flight).
// ---------------------------------------------------------------------------
__global__ __launch_bounds__(256) void k_edge(const f4* __restrict__ w,
                                              const i4* __restrict__ r,
                                              const __half* __restrict__ recip,
                                              f4* __restrict__ out) {
    const int nq = N_EDGES / 16;                     // 1,562,500 (exact)
    int tid = blockIdx.x * blockDim.x + threadIdx.x;
    int stride = gridDim.x * blockDim.x;
    for (int q = tid; q < nq; q += stride) {
        int v = q * 4;
        i4 u0 = __builtin_nontemporal_load(&r[v + 0]);
        i4 u1 = __builtin_nontemporal_load(&r[v + 1]);
        i4 u2 = __builtin_nontemporal_load(&r[v + 2]);
        i4 u3 = __builtin_nontemporal_load(&r[v + 3]);
        f4 a0 = __builtin_nontemporal_load(&w[v + 0]);
        f4 a1 = __builtin_nontemporal_load(&w[v + 1]);
        f4 a2 = __builtin_nontemporal_load(&w[v + 2]);
        f4 a3 = __builtin_nontemporal_load(&w[v + 3]);
        float g0  = __half2float(recip[u0.x]);
        float g1  = __half2float(recip[u0.y]);
        float g2  = __half2float(recip[u0.z]);
        float g3  = __half2float(recip[u0.w]);
        float g4  = __half2float(recip[u1.x]);
        float g5  = __half2float(recip[u1.y]);
        float g6  = __half2float(recip[u1.z]);
        float g7  = __half2float(recip[u1.w]);
        float g8  = __half2float(recip[u2.x]);
        float g9  = __half2float(recip[u2.y]);
        float g10 = __half2float(recip[u2.z]);
        float g11 = __half2float(recip[u2.w]);
        float g12 = __half2float(recip[u3.x]);
        float g13 = __half2float(recip[u3.y]);
        float g14 = __half2float(recip[u3.z]);
        float g15 = __half2float(recip[u3.w]);
        __builtin_amdgcn_sched_barrier(0);
        f4 o;
        o.x = __expf(a0.x) * g0;
        o.y = __expf(a0.y) * g1;
        o.z = __expf(a0.z) * g2;
        o.w = __expf(a0.w) * g3;
        __builtin_nontemporal_store(o, &out[v + 0]);
        o.x = __expf(a1.x) * g4;
        o.y = __expf(a1.y) * g5;
        o.z = __expf(a1.z) * g6;
        o.w = __expf(a1.w) * g7;
        __builtin_nontemporal_store(o, &out[v + 1]);
        o.x = __expf(a2.x) * g8;
        o.y = __expf(a2.y) * g9;
        o.z = __expf(a2.z) * g10;
        o.w = __expf(a2.w) * g11;
        __builtin_nontemporal_store(o, &out[v + 2]);
        o.x = __expf(a3.x) * g12;
        o.y = __expf(a3.y) * g13;
        o.z = __expf(a3.z) * g14;
        o.w = __expf(a3.w) * g15;
        __builtin_nontemporal_store(o, &out[v + 3]);
    }
}

extern "C" void kernel_launch(void* const* d_in, const int* in_sizes, int n_in,
                              void* d_out, int out_size, void* d_ws, size_t ws_size,
                              hipStream_t stream) {
    const float* w0 = (const float*)d_in[0];
    const float* w1 = (const float*)d_in[1];
    const float* w2 = (const float*)d_in[2];
    const int* r1 = (const int*)d_in[3];
    const int* r2 = (const int*)d_in[4];

    float* out = (float*)d_out;
    float* lfw0 = out;                        // [N_USERS]
    float* lfw1 = out + N_USERS;              // [N_EDGES]
    float* lfw2 = out + N_USERS + N_EDGES;    // [N_EDGES]

    // Scratch payloads live in the lfw1/lfw2 region (2x 100 MB): fully
    // consumed by k_bucket_seq before the k_edge kernels overwrite them.
    uint32_t* payloadA = (uint32_t*)(out + N_USERS);          // tile-sorted
    uint32_t* payloadB = payloadA + N_EDGES;                  // globally sorted

    float* ws = (float*)d_ws;
    __half* recip1 = (__half*)ws;                             // 2 MB
    __half* recip2 = recip1 + N_USERS;                        // 0.4 MB
    uint32_t* starts    = (uint32_t*)(recip2 + N_ITEMS);      // RUNS*(NB_U+1)
    uint32_t* startsT   = starts + (size_t)RUNS * (NB_U + 1);
    uint32_t* pre       = startsT + (size_t)RUNS * (NB_U + 1);
    uint32_t* bsum      = pre + (size_t)NB_U * RUNS;
    uint32_t* gstart_rb = bsum + 1024;                        // RUNS*NB_U

    // ---------------- Relation 1 (users) ----------------
    k_part<SHIFT_U, NB_U><<<NBLK, 1024, 0, stream>>>(w1, r1, payloadA, starts);
    {
        dim3 g((NB_U + 1 + 31) / 32, (RUNS + 31) / 32);
        k_transpose<<<g, 1024, 0, stream>>>(starts, startsT, RUNS, NB_U + 1);
    }
    k_scanA<NB_U><<<SCB_U, 1024, 0, stream>>>(startsT, pre, bsum);
    k_scanB<<<1, 1024, 0, stream>>>(bsum, SCB_U);
    k_scanC<NB_U><<<SCB_U, 1024, 0, stream>>>(pre, bsum, gstart_rb);
    k_scatter<NB_U><<<RUNS, 1024, 0, stream>>>(payloadA, starts, gstart_rb, payloadB);
    k_bucket_seq<SHIFT_U, NB_U><<<NB_U, 1024, 0, stream>>>(payloadB, gstart_rb,
                                                           N_USERS, w0, recip1, lfw0);

    // ---------------- Relation 2 (items) ----------------
    k_part<SHIFT_I, NB_I><<<NBLK, 1024, 0, stream>>>(w2, r2, payloadA, starts);
    {
        dim3 g((NB_I + 1 + 31) / 32, (RUNS + 31) / 32);
        k_transpose<<<g, 1024, 0, stream>>>(starts, startsT, RUNS, NB_I + 1);
    }
    k_scanA<NB_I><<<SCB_I, 1024, 0, stream>>>(startsT, pre, bsum);
    k_scanB<<<1, 1024, 0, stream>>>(bsum, SCB_I);
    k_scanC<NB_I><<<SCB_I, 1024, 0, stream>>>(pre, bsum, gstart_rb);
    k_scatter<NB_I><<<RUNS, 1024, 0, stream>>>(payloadA, starts, gstart_rb, payloadB);
    k_bucket_seq<SHIFT_I, NB_I><<<NB_I, 1024, 0, stream>>>(payloadB, gstart_rb,
                                                           N_ITEMS, nullptr, recip2, nullptr);

    // ---------------- Per-edge finalize ----------------
    k_edge<<<2048, 256, 0, stream>>>((const f4*)w1, (const i4*)r1, recip1, (f4*)lfw1);
    k_edge<<<2048, 256, 0, stream>>>((const f4*)w2, (const i4*)r2, recip2, (f4*)lfw2);
}

// Round 13
// 516.406 us; speedup vs baseline: 2.0349x; 2.0349x over previous
//
#include <hip/hip_runtime.h>
#include <hip/hip_fp16.h>
#include <stdint.h>

static constexpr int N_USERS = 1000000;
static constexpr int N_ITEMS = 200000;
static constexpr int N_EDGES = 25000000;

// Tile/partition geometry
static constexpr int TILE   = 16384;                 // edges per LDS-sorted tile
static constexpr int NTILES = 3;
static constexpr int CHUNK  = TILE * NTILES;         // 49152 edges per block
static constexpr int NBLK   = (N_EDGES + CHUNK - 1) / CHUNK;   // 509
static constexpr int RUNS   = NBLK * NTILES;         // runs per bucket = 1527

static constexpr int SHIFT_U = 11;                   // users: 2048 bins/bucket
static constexpr int SHIFT_I = 9;                    // items:  512 bins/bucket
static constexpr int NB_U = (N_USERS + (1 << SHIFT_U) - 1) >> SHIFT_U;  // 489
static constexpr int NB_I = (N_ITEMS + (1 << SHIFT_I) - 1) >> SHIFT_I;  // 391

// Fixed-point scale for u32 LDS accumulation (integer LDS atomics are
// full-rate; ds_add_f32 measured ~4cy/lane across rounds 6-12).
static constexpr float FPSCALE  = 32768.0f;          // 2^15
static constexpr float FPINV    = 1.0f / 32768.0f;

typedef float    f4 __attribute__((ext_vector_type(4)));
typedef int      i4 __attribute__((ext_vector_type(4)));
typedef uint32_t u4 __attribute__((ext_vector_type(4)));

// ---------------------------------------------------------------------------
// P1: per-block tile-sorted partition (round-9 structure, unchanged).
// ---------------------------------------------------------------------------
template<int SHIFT, int NB>
__global__ __launch_bounds__(1024) void k_part(const float* __restrict__ w,
                                               const int* __restrict__ r,
                                               uint32_t* __restrict__ payload,
                                               uint32_t* __restrict__ starts) {
    __shared__ uint32_t stage[TILE];     // 64 KB
    __shared__ uint32_t hist[1024];      // histogram, then write cursors
    __shared__ uint32_t wsum[16];
    const int blk = blockIdx.x;
    const int t = threadIdx.x;
    const int lane = t & 63, wave = t >> 6;
    const int begin = blk * CHUNK;
    const int bend = (begin + CHUNK < N_EDGES) ? begin + CHUNK : N_EDGES;
    const uint32_t lmask = (1u << SHIFT) - 1u;

    for (int tile = 0; tile < NTILES; ++tile) {
        const int tb = begin + tile * TILE;
        int n = bend - tb;
        n = n < 0 ? 0 : (n > TILE ? TILE : n);
        const int n4 = n >> 2;                       // all boundaries %4 == 0
        const size_t mbase = (size_t)(blk * NTILES + tile) * (NB + 1);

        hist[t] = 0;
        __syncthreads();

        // 1) load r+w, build payload in regs, histogram
        uint32_t idx[16];
        uint32_t pay[16];
        #pragma unroll
        for (int k = 0; k < 4; ++k) {
            int v = t + k * 1024;
            if (v < n4) {
                i4 u = __builtin_nontemporal_load((const i4*)r + (tb >> 2) + v);
                f4 a = __builtin_nontemporal_load((const f4*)w + (tb >> 2) + v);
                idx[4 * k + 0] = (uint32_t)u.x;
                idx[4 * k + 1] = (uint32_t)u.y;
                idx[4 * k + 2] = (uint32_t)u.z;
                idx[4 * k + 3] = (uint32_t)u.w;
                pay[4 * k + 0] = (__float_as_uint(__expf(a.x)) & ~lmask) | ((uint32_t)u.x & lmask);
                pay[4 * k + 1] = (__float_as_uint(__expf(a.y)) & ~lmask) | ((uint32_t)u.y & lmask);
                pay[4 * k + 2] = (__float_as_uint(__expf(a.z)) & ~lmask) | ((uint32_t)u.z & lmask);
                pay[4 * k + 3] = (__float_as_uint(__expf(a.w)) & ~lmask) | ((uint32_t)u.w & lmask);
                atomicAdd(&hist[(uint32_t)u.x >> SHIFT], 1u);
                atomicAdd(&hist[(uint32_t)u.y >> SHIFT], 1u);
                atomicAdd(&hist[(uint32_t)u.z >> SHIFT], 1u);
                atomicAdd(&hist[(uint32_t)u.w >> SHIFT], 1u);
            }
        }
        __syncthreads();

        // 2) exclusive scan of hist[0..1023] (entries >= NB are zero)
        uint32_t c = hist[t];
        uint32_t x = c;
        #pragma unroll
        for (int d = 1; d < 64; d <<= 1) {
            uint32_t y = __shfl_up(x, d);
            if (lane >= d) x += y;
        }
        if (lane == 63) wsum[wave] = x;
        __syncthreads();
        if (t < 16) {
            uint32_t y = wsum[t];
            uint32_t s = y;
            #pragma unroll
            for (int d = 1; d < 16; d <<= 1) {
                uint32_t z = __shfl_up(s, d, 16);
                if (t >= d) s += z;
            }
            wsum[t] = s - y;                         // exclusive wave prefix
        }
        __syncthreads();
        uint32_t excl = x - c + wsum[wave];

        if (t < NB) starts[mbase + t] = (uint32_t)tb + excl;
        if (t == 0) starts[mbase + NB] = (uint32_t)(tb + n);  // sentinel
        hist[t] = excl;                              // tile-local cursors
        __syncthreads();

        // 3) scatter into LDS stage (registers only)
        #pragma unroll
        for (int k = 0; k < 4; ++k) {
            int v = t + k * 1024;
            if (v < n4) {
                uint32_t p0 = atomicAdd(&hist[idx[4 * k + 0] >> SHIFT], 1u);
                stage[p0] = pay[4 * k + 0];
                uint32_t p1 = atomicAdd(&hist[idx[4 * k + 1] >> SHIFT], 1u);
                stage[p1] = pay[4 * k + 1];
                uint32_t p2 = atomicAdd(&hist[idx[4 * k + 2] >> SHIFT], 1u);
                stage[p2] = pay[4 * k + 2];
                uint32_t p3 = atomicAdd(&hist[idx[4 * k + 3] >> SHIFT], 1u);
                stage[p3] = pay[4 * k + 3];
            }
        }
        __syncthreads();

        // 4) coalesced dump of the sorted tile
        #pragma unroll
        for (int k = 0; k < 4; ++k) {
            int v = t + k * 1024;
            if (v < n4) {
                u4 s4 = ((const u4*)stage)[v];
                __builtin_nontemporal_store(s4, (u4*)payload + (tb >> 2) + v);
            }
        }
        __syncthreads();                             // before next tile's hist[]=0
    }
}

// ---------------------------------------------------------------------------
// Tiled transpose: in[R][C] -> outT[C][R].
// ---------------------------------------------------------------------------
__global__ __launch_bounds__(1024) void k_transpose(const uint32_t* __restrict__ in,
                                                    uint32_t* __restrict__ outT,
                                                    int R, int C) {
    __shared__ uint32_t tile[32][33];
    const int tx = threadIdx.x & 31, ty = threadIdx.x >> 5;
    const int r0 = blockIdx.y * 32, c0 = blockIdx.x * 32;
    int r = r0 + ty, c = c0 + tx;
    if (r < R && c < C) tile[ty][tx] = in[(size_t)r * C + c];
    __syncthreads();
    int rr = r0 + tx, cc = c0 + ty;
    if (cc < C && rr < R) outT[(size_t)cc * R + rr] = tile[tx][ty];
}

// ---------------------------------------------------------------------------
// P2: one block per bucket (round-9 structure) with U32 FIXED-POINT LDS
// atomics: integer ds_add is full-rate (k_part proves it), while ds_add_f32
// measured ~4cy/lane across 6 structural variants. exp scaled by 2^15;
// worst-case bin sum < 2^17 so u32 can't overflow. Run bounds preloaded to
// registers; 1-deep prefetch. Emits f16 reciprocals; users variant fuses
// exp(w0) self term + lfw0.
// ---------------------------------------------------------------------------
template<int SHIFT, int NB>
__global__ __launch_bounds__(1024) void k_bucket(const uint32_t* __restrict__ payload,
                                                 const uint32_t* __restrict__ startsT, // [NB+1][RUNS]
                                                 int nelems,
                                                 const float* __restrict__ w0,   // null for items
                                                 __half* __restrict__ recip,
                                                 float* __restrict__ lfw0) {     // null for items
    constexpr int BINS = 1 << SHIFT;
    constexpr int KMAX = (RUNS + 127) / 128;         // 12
    __shared__ uint32_t binsU[BINS];
    __shared__ uint32_t srow[RUNS];
    __shared__ uint32_t erow[RUNS];
    const int b = blockIdx.x;
    const int t = threadIdx.x;
    for (int i = t; i < BINS; i += 1024) binsU[i] = 0u;
    const uint32_t* s0 = startsT + (size_t)b * RUNS;
    const uint32_t* e0 = startsT + (size_t)(b + 1) * RUNS;
    for (int i = t; i < RUNS; i += 1024) {
        srow[i] = s0[i];
        erow[i] = e0[i];
    }
    __syncthreads();

    const int sub = t >> 3, sl = t & 7;              // 128 subgroups of 8 lanes

    // Preload this subgroup's run bounds into registers.
    uint32_t sk[KMAX], ek[KMAX];
    #pragma unroll
    for (int k = 0; k < KMAX; ++k) {
        int run = sub + (k << 7);
        bool ok = run < RUNS;
        sk[k] = ok ? srow[run] : 0u;
        ek[k] = ok ? erow[run] : 0u;
    }

    const u4* payload4 = (const u4*)payload;
    #pragma unroll
    for (int k = 0; k < KMAX; ++k) {
        uint32_t s = sk[k], e = ek[k];
        uint32_t j  = (s >> 2) + sl;
        uint32_t j1 = (e + 3) >> 2;
        bool have = j < j1;
        u4 cur;
        if (have) cur = __builtin_nontemporal_load(&payload4[j]);
        while (have) {
            uint32_t jn = j + 8;
            bool haveN = jn < j1;
            u4 nxt;
            if (haveN) nxt = __builtin_nontemporal_load(&payload4[jn]); // in flight
            uint32_t g = j << 2;
            #pragma unroll
            for (int c = 0; c < 4; ++c) {
                uint32_t gg = g + c;
                if (gg >= s && gg < e) {
                    uint32_t p = cur[c];
                    float ev = __uint_as_float(p & ~(uint32_t)(BINS - 1));
                    atomicAdd(&binsU[p & (BINS - 1)],
                              (uint32_t)(ev * FPSCALE + 0.5f));
                }
            }
            j = jn;
            cur = nxt;
            have = haveN;
        }
    }
    __syncthreads();

    for (int i = t; i < BINS; i += 1024) {
        int g = b * BINS + i;
        if (g < nelems) {
            float s = (float)binsU[i] * FPINV;
            if (w0) {
                float e = __expf(w0[g]);
                s += e;
                lfw0[g] = e / s;
            }
            recip[g] = __float2half(1.0f / s);
        }
    }
}

// ---------------------------------------------------------------------------
// Per-edge finalize for ONE relation, unrolled x4 (16 gathers in flight).
// ---------------------------------------------------------------------------
__global__ __launch_bounds__(256) void k_edge(const f4* __restrict__ w,
                                              const i4* __restrict__ r,
                                              const __half* __restrict__ recip,
                                              f4* __restrict__ out) {
    const int nq = N_EDGES / 16;                     // 1,562,500 (exact)
    int tid = blockIdx.x * blockDim.x + threadIdx.x;
    int stride = gridDim.x * blockDim.x;
    for (int q = tid; q < nq; q += stride) {
        int v = q * 4;
        i4 u0 = __builtin_nontemporal_load(&r[v + 0]);
        i4 u1 = __builtin_nontemporal_load(&r[v + 1]);
        i4 u2 = __builtin_nontemporal_load(&r[v + 2]);
        i4 u3 = __builtin_nontemporal_load(&r[v + 3]);
        float g0  = __half2float(recip[u0.x]);
        float g1  = __half2float(recip[u0.y]);
        float g2  = __half2float(recip[u0.z]);
        float g3  = __half2float(recip[u0.w]);
        float g4  = __half2float(recip[u1.x]);
        float g5  = __half2float(recip[u1.y]);
        float g6  = __half2float(recip[u1.z]);
        float g7  = __half2float(recip[u1.w]);
        float g8  = __half2float(recip[u2.x]);
        float g9  = __half2float(recip[u2.y]);
        float g10 = __half2float(recip[u2.z]);
        float g11 = __half2float(recip[u2.w]);
        float g12 = __half2float(recip[u3.x]);
        float g13 = __half2float(recip[u3.y]);
        float g14 = __half2float(recip[u3.z]);
        float g15 = __half2float(recip[u3.w]);
        f4 a0 = __builtin_nontemporal_load(&w[v + 0]);
        f4 a1 = __builtin_nontemporal_load(&w[v + 1]);
        f4 a2 = __builtin_nontemporal_load(&w[v + 2]);
        f4 a3 = __builtin_nontemporal_load(&w[v + 3]);
        f4 o;
        o.x = __expf(a0.x) * g0;
        o.y = __expf(a0.y) * g1;
        o.z = __expf(a0.z) * g2;
        o.w = __expf(a0.w) * g3;
        __builtin_nontemporal_store(o, &out[v + 0]);
        o.x = __expf(a1.x) * g4;
        o.y = __expf(a1.y) * g5;
        o.z = __expf(a1.z) * g6;
        o.w = __expf(a1.w) * g7;
        __builtin_nontemporal_store(o, &out[v + 1]);
        o.x = __expf(a2.x) * g8;
        o.y = __expf(a2.y) * g9;
        o.z = __expf(a2.z) * g10;
        o.w = __expf(a2.w) * g11;
        __builtin_nontemporal_store(o, &out[v + 2]);
        o.x = __expf(a3.x) * g12;
        o.y = __expf(a3.y) * g13;
        o.z = __expf(a3.z) * g14;
        o.w = __expf(a3.w) * g15;
        __builtin_nontemporal_store(o, &out[v + 3]);
    }
}

extern "C" void kernel_launch(void* const* d_in, const int* in_sizes, int n_in,
                              void* d_out, int out_size, void* d_ws, size_t ws_size,
                              hipStream_t stream) {
    const float* w0 = (const float*)d_in[0];
    const float* w1 = (const float*)d_in[1];
    const float* w2 = (const float*)d_in[2];
    const int* r1 = (const int*)d_in[3];
    const int* r2 = (const int*)d_in[4];

    float* out = (float*)d_out;
    float* lfw0 = out;                        // [N_USERS]
    float* lfw1 = out + N_USERS;              // [N_EDGES]
    float* lfw2 = out + N_USERS + N_EDGES;    // [N_EDGES]

    // Scratch payload (100 MB) lives in the lfw1/lfw2 region (200 MB): it is
    // fully consumed by k_bucket before the k_edge kernels overwrite it.
    uint32_t* payload = (uint32_t*)(out + N_USERS);

    float* ws = (float*)d_ws;
    __half* recip1 = (__half*)ws;                       // [N_USERS]  (2 MB)
    __half* recip2 = recip1 + N_USERS;                  // [N_ITEMS]  (0.4 MB)
    uint32_t* starts  = (uint32_t*)(recip2 + N_ITEMS);  // [RUNS*(NB_U+1)] ~3 MB
    uint32_t* startsT = starts + (size_t)RUNS * (NB_U + 1);  // [(NB_U+1)*RUNS] ~3 MB

    // Relation 1 (users)
    k_part<SHIFT_U, NB_U><<<NBLK, 1024, 0, stream>>>(w1, r1, payload, starts);
    {
        dim3 g((NB_U + 1 + 31) / 32, (RUNS + 31) / 32);
        k_transpose<<<g, 1024, 0, stream>>>(starts, startsT, RUNS, NB_U + 1);
    }
    k_bucket<SHIFT_U, NB_U><<<NB_U, 1024, 0, stream>>>(payload, startsT,
                                                       N_USERS, w0, recip1, lfw0);

    // Relation 2 (items) — reuses payload/starts/startsT
    k_part<SHIFT_I, NB_I><<<NBLK, 1024, 0, stream>>>(w2, r2, payload, starts);
    {
        dim3 g((NB_I + 1 + 31) / 32, (RUNS + 31) / 32);
        k_transpose<<<g, 1024, 0, stream>>>(starts, startsT, RUNS, NB_I + 1);
    }
    k_bucket<SHIFT_I, NB_I><<<NB_I, 1024, 0, stream>>>(payload, startsT,
                                                       N_ITEMS, nullptr, recip2, nullptr);

    // Per-edge finalize (payload fully consumed; safe to overwrite lfw1)
    k_edge<<<2048, 256, 0, stream>>>((const f4*)w1, (const i4*)r1, recip1, (f4*)lfw1);
    k_edge<<<2048, 256, 0, stream>>>((const f4*)w2, (const i4*)r2, recip2, (f4*)lfw2);
}